// Round 1
// baseline (140.295 us; speedup 1.0000x reference)
//
#include <hip/hip_runtime.h>
#include <hip/hip_cooperative_groups.h>

namespace cg = cooperative_groups;

#define Bsz 128
#define Csz 1024
#define Nsz 512
#define NCsz 1024
#define CAP 64     // max body literals per clause per sign; E=10.2, P(>64)~0
#define NBLK 256   // 1 block per CU -> cheapest grid barrier
#define NTHR 512   // 4 clauses/block (128 thr each); 256*512 = 131072 = B*NC output elems

// Single cooperative kernel, 3 phases split by grid.sync():
//  A: zero bounds + gather mT (coalesced col writes) + clause scan -> lists in LDS + inv table
//  B: body_min per (clause, b) + float-bits atomicMax into lb/ub bounds
//  C: one thread per output element: clamp atoms via inv[] / pass-through, fully coalesced
__global__ __launch_bounds__(NTHR) void k_fused(
    const float* __restrict__ preds,
    const float* __restrict__ pos_head, const float* __restrict__ neg_head,
    const float* __restrict__ pos_body, const float* __restrict__ neg_body,
    const int* __restrict__ atoms,
    float* __restrict__ mT,            // ws: 65536 f32, mT[n][b]
    unsigned* __restrict__ bounds,     // ws: lbmax[65536] ++ ubmax[65536], contiguous
    float* __restrict__ out)
{
    __shared__ int   plist[4][CAP];
    __shared__ int   nlist[4][CAP];
    __shared__ int   cnts[4][2];
    __shared__ int   headn[4];
    __shared__ int   headsg[4];
    __shared__ short inv[NCsz];        // inv[class j] = atom index n, or -1

    cg::grid_group grid = cg::this_grid();
    const int g   = blockIdx.x;
    const int tid = threadIdx.x;

    unsigned* lbmax = bounds;
    unsigned* ubmax = bounds + Bsz * Nsz;

    // ---------------- Phase A ----------------
    if (tid < 8) cnts[tid >> 1][tid & 1] = 0;
    inv[2 * tid]     = -1;
    inv[2 * tid + 1] = -1;
    __syncthreads();                   // cnts/inv init visible before scan/scatter

    inv[atoms[tid]] = (short)tid;      // NTHR == Nsz: one scatter per thread

    // zero lbmax||ubmax: 131072 u32 over 256 blocks, coalesced, 1 per thread
    bounds[g * NTHR + tid] = 0u;

    // gather two mT columns per block: write-coalesced (512B per wave-pair),
    // reads are a stride-4KB gather of preds but each 64B line is L2-reused ~8x
    if (tid < 2 * Bsz) {
        int col = 2 * g + (tid >> 7);
        int b   = tid & (Bsz - 1);
        mT[col * Bsz + b] = preds[b * NCsz + atoms[col]];
    }

    // clause structure scan: 4 clauses/block, 128 threads x float4 = full 512-row
    {
        int cl = tid >> 7, q = tid & 127;
        int c  = 4 * g + cl;
        int n0 = q * 4;
        float4 p  = ((const float4*)(pos_body + c * Nsz))[q];
        float4 nb = ((const float4*)(neg_body + c * Nsz))[q];
        float4 ph = ((const float4*)(pos_head + c * Nsz))[q];
        float4 nh = ((const float4*)(neg_head + c * Nsz))[q];
        if (p.x  != 0.f) { int s = atomicAdd(&cnts[cl][0], 1); if (s < CAP) plist[cl][s] = n0;     }
        if (p.y  != 0.f) { int s = atomicAdd(&cnts[cl][0], 1); if (s < CAP) plist[cl][s] = n0 + 1; }
        if (p.z  != 0.f) { int s = atomicAdd(&cnts[cl][0], 1); if (s < CAP) plist[cl][s] = n0 + 2; }
        if (p.w  != 0.f) { int s = atomicAdd(&cnts[cl][0], 1); if (s < CAP) plist[cl][s] = n0 + 3; }
        if (nb.x != 0.f) { int s = atomicAdd(&cnts[cl][1], 1); if (s < CAP) nlist[cl][s] = n0;     }
        if (nb.y != 0.f) { int s = atomicAdd(&cnts[cl][1], 1); if (s < CAP) nlist[cl][s] = n0 + 1; }
        if (nb.z != 0.f) { int s = atomicAdd(&cnts[cl][1], 1); if (s < CAP) nlist[cl][s] = n0 + 2; }
        if (nb.w != 0.f) { int s = atomicAdd(&cnts[cl][1], 1); if (s < CAP) nlist[cl][s] = n0 + 3; }
        if (ph.x != 0.f) { headn[cl] = n0;     headsg[cl] = 1; }
        if (ph.y != 0.f) { headn[cl] = n0 + 1; headsg[cl] = 1; }
        if (ph.z != 0.f) { headn[cl] = n0 + 2; headsg[cl] = 1; }
        if (ph.w != 0.f) { headn[cl] = n0 + 3; headsg[cl] = 1; }
        if (nh.x != 0.f) { headn[cl] = n0;     headsg[cl] = 0; }
        if (nh.y != 0.f) { headn[cl] = n0 + 1; headsg[cl] = 0; }
        if (nh.z != 0.f) { headn[cl] = n0 + 2; headsg[cl] = 0; }
        if (nh.w != 0.f) { headn[cl] = n0 + 3; headsg[cl] = 0; }
    }

    grid.sync();   // mT + zeroed bounds visible device-wide; LDS lists ready

    // ---------------- Phase B ----------------
    // clause c = 4g+cl, thread b: body_min = 1 - max over literals; bm in [0,1]
    // -> float bits monotone -> uint atomicMax exact. mT reads 512B-coalesced.
    {
        int cl = tid >> 7, b = tid & 127;
        int pc = min(cnts[cl][0], CAP);
        int nc = min(cnts[cl][1], CAP);
        float acc = 0.f;
        for (int e = 0; e < pc; e++) acc = fmaxf(acc, 1.f - mT[plist[cl][e] * Bsz + b]);
        for (int e = 0; e < nc; e++) acc = fmaxf(acc, mT[nlist[cl][e] * Bsz + b]);
        unsigned* dst = headsg[cl] ? lbmax : ubmax;   // pos head -> lb, neg head -> ub
        atomicMax(dst + headn[cl] * Bsz + b, __float_as_uint(1.f - acc));
    }

    grid.sync();   // all bounds final

    // ---------------- Phase C ----------------
    // one thread per output element, j-fast: preds read + out write coalesced
    {
        int t = g * NTHR + tid;
        int b = t >> 10, j = t & (NCsz - 1);
        float v = preds[b * NCsz + j];
        int n = inv[j];
        if (n >= 0) {
            float lb = __uint_as_float(lbmax[n * Bsz + b]);
            float ub = 1.f - __uint_as_float(ubmax[n * Bsz + b]);
            float lo = fminf(lb, ub), hi = fmaxf(lb, ub);
            v = fmaxf(lo, fminf(hi, v));
        }
        out[b * NCsz + j] = v;
    }
}

extern "C" void kernel_launch(void* const* d_in, const int* in_sizes, int n_in,
                              void* d_out, int out_size, void* d_ws, size_t ws_size,
                              hipStream_t stream)
{
    const float* preds    = (const float*)d_in[0];
    const float* pos_head = (const float*)d_in[1];
    const float* neg_head = (const float*)d_in[2];
    const float* pos_body = (const float*)d_in[3];
    const float* neg_body = (const float*)d_in[4];
    const int*   atoms    = (const int*)d_in[5];
    float* out = (float*)d_out;

    char* ws = (char*)d_ws;
    float*    mT     = (float*)ws;                    // 65536 f32
    unsigned* bounds = (unsigned*)(ws + 65536u * 4);  // 131072 u32 (lbmax ++ ubmax)

    void* args[] = {
        (void*)&preds, (void*)&pos_head, (void*)&neg_head,
        (void*)&pos_body, (void*)&neg_body, (void*)&atoms,
        (void*)&mT, (void*)&bounds, (void*)&out
    };
    hipLaunchCooperativeKernel((const void*)k_fused, dim3(NBLK), dim3(NTHR),
                               args, 0, stream);
}

// Round 2
// 84.207 us; speedup vs baseline: 1.6661x; 1.6661x over previous
//
#include <hip/hip_runtime.h>

#define Bsz 128
#define Csz 1024
#define Nsz 512
#define NCsz 1024
#define CAP 64     // max body literals per clause per sign; E=10.2, P(>64)~0 (verified absmax=0)
#define MCAP 32    // max clauses per head atom; E=2 (Binomial(1024,1/512)), P(>32)~0
#define NT2 512

// ---------------- Kernel 1: gather mT + clause scan -> lists + head_of ----------------
// blocks   0..255: gather mT[col][b] = preds[b][atoms[col]], 2 cols/block, b-fast
//                  (coalesced 256B writes; preds reads are stride-4KB but L2-resident)
// blocks 256..511: wave-per-clause float4 scan -> literal lists + head_of[c]=(n<<1)|sign
// No bounds buffer, no zeroing, no atomicMax anywhere.
__global__ __launch_bounds__(256) void k_scan(
    const float* __restrict__ preds,
    const float* __restrict__ pos_head, const float* __restrict__ neg_head,
    const float* __restrict__ pos_body, const float* __restrict__ neg_body,
    const int* __restrict__ atoms,
    float* __restrict__ mT,
    int* __restrict__ pos_list, int* __restrict__ neg_list,
    int* __restrict__ pos_cnt, int* __restrict__ neg_cnt,
    int* __restrict__ head_of)
{
    int blk = blockIdx.x, tid = threadIdx.x;
    if (blk < 256) {
        int b   = tid & (Bsz - 1);
        int col = 2 * blk + (tid >> 7);
        mT[col * Bsz + b] = preds[b * NCsz + atoms[col]];
    } else {
        __shared__ int cnts[4][2];
        int wave = tid >> 6, lane = tid & 63;
        int c = (blk - 256) * 4 + wave;
        if (lane == 0) { cnts[wave][0] = 0; cnts[wave][1] = 0; }
        // per-wave LDS counters, wave-ordered stream: no barrier needed (round-0-verified)
        const float4* pb4 = (const float4*)(pos_body + c * Nsz);
        const float4* nb4 = (const float4*)(neg_body + c * Nsz);
        const float4* ph4 = (const float4*)(pos_head + c * Nsz);
        const float4* nh4 = (const float4*)(neg_head + c * Nsz);
        for (int k = 0; k < 2; k++) {
            int q = k * 64 + lane;                // float4 index, n0 = 4*q
            float4 p  = pb4[q];
            float4 nb = nb4[q];
            float4 ph = ph4[q];
            float4 nh = nh4[q];
            int n0 = q * 4;
            if (p.x  != 0.f) { int s = atomicAdd(&cnts[wave][0], 1); if (s < CAP) pos_list[c * CAP + s] = n0;     }
            if (p.y  != 0.f) { int s = atomicAdd(&cnts[wave][0], 1); if (s < CAP) pos_list[c * CAP + s] = n0 + 1; }
            if (p.z  != 0.f) { int s = atomicAdd(&cnts[wave][0], 1); if (s < CAP) pos_list[c * CAP + s] = n0 + 2; }
            if (p.w  != 0.f) { int s = atomicAdd(&cnts[wave][0], 1); if (s < CAP) pos_list[c * CAP + s] = n0 + 3; }
            if (nb.x != 0.f) { int s = atomicAdd(&cnts[wave][1], 1); if (s < CAP) neg_list[c * CAP + s] = n0;     }
            if (nb.y != 0.f) { int s = atomicAdd(&cnts[wave][1], 1); if (s < CAP) neg_list[c * CAP + s] = n0 + 1; }
            if (nb.z != 0.f) { int s = atomicAdd(&cnts[wave][1], 1); if (s < CAP) neg_list[c * CAP + s] = n0 + 2; }
            if (nb.w != 0.f) { int s = atomicAdd(&cnts[wave][1], 1); if (s < CAP) neg_list[c * CAP + s] = n0 + 3; }
            if (ph.x != 0.f) head_of[c] = ((n0    ) << 1) | 1;
            if (ph.y != 0.f) head_of[c] = ((n0 + 1) << 1) | 1;
            if (ph.z != 0.f) head_of[c] = ((n0 + 2) << 1) | 1;
            if (ph.w != 0.f) head_of[c] = ((n0 + 3) << 1) | 1;
            if (nh.x != 0.f) head_of[c] = ((n0    ) << 1);
            if (nh.y != 0.f) head_of[c] = ((n0 + 1) << 1);
            if (nh.z != 0.f) head_of[c] = ((n0 + 2) << 1);
            if (nh.w != 0.f) head_of[c] = ((n0 + 3) << 1);
        }
        if (lane == 0) {
            pos_cnt[c] = min(cnts[wave][0], CAP);
            neg_cnt[c] = min(cnts[wave][1], CAP);
        }
    }
}

// ---------------- Kernel 2: per-atom bounds + clamp + pass-through ----------------
// blocks 0..511: atom n. Scan head_of (4KB, L2-broadcast) -> matched clause list in LDS;
//                4-way clause split across 512 threads (kills max-degree tail), LDS combine,
//                clamp and write atom column. No cross-block dependency.
// blocks 512..575: pass-through, 2048 elems/block, j-fast coalesced, LDS is-atom table.
__global__ __launch_bounds__(NT2) void k_apply(
    const float* __restrict__ preds,
    const float* __restrict__ mT,
    const int* __restrict__ pos_list, const int* __restrict__ neg_list,
    const int* __restrict__ pos_cnt, const int* __restrict__ neg_cnt,
    const int* __restrict__ head_of,
    const int* __restrict__ atoms,
    float* __restrict__ out)
{
    int blk = blockIdx.x, tid = threadIdx.x;
    if (blk < Nsz) {
        __shared__ int   matched[MCAP];
        __shared__ int   mcnt;
        __shared__ float lbs[4][Bsz];
        __shared__ float ubs[4][Bsz];
        const int n = blk;
        if (tid == 0) mcnt = 0;
        __syncthreads();
        for (int i = tid; i < Csz; i += NT2) {      // 2 iters: find my head clauses
            int h = head_of[i];
            if ((h >> 1) == n) {
                int s = atomicAdd(&mcnt, 1);
                if (s < MCAP) matched[s] = (i << 1) | (h & 1);
            }
        }
        __syncthreads();
        int q = tid >> 7, b = tid & (Bsz - 1);      // 4 clause-lanes x 128 batch
        float lb = 0.f, ubm = 0.f;
        int mc = min(mcnt, MCAP);
        for (int k = q; k < mc; k += 4) {
            int c    = matched[k] >> 1;
            int sign = matched[k] & 1;
            const int* pl = pos_list + c * CAP;
            const int* nl = neg_list + c * CAP;
            int pc = pos_cnt[c], nc = neg_cnt[c];
            float acc = 0.f;                         // mT reads: 256B coalesced, L2-hit
            for (int e = 0; e < pc; e++) acc = fmaxf(acc, 1.f - mT[pl[e] * Bsz + b]);
            for (int e = 0; e < nc; e++) acc = fmaxf(acc, mT[nl[e] * Bsz + b]);
            float bm = 1.f - acc;                    // body_min in [0,1]
            if (sign) lb = fmaxf(lb, bm); else ubm = fmaxf(ubm, bm);
        }
        lbs[q][b] = lb; ubs[q][b] = ubm;
        __syncthreads();
        if (q == 0) {
            lb  = fmaxf(fmaxf(lbs[0][b], lbs[1][b]), fmaxf(lbs[2][b], lbs[3][b]));
            ubm = fmaxf(fmaxf(ubs[0][b], ubs[1][b]), fmaxf(ubs[2][b], ubs[3][b]));
            float ub = 1.f - ubm;                    // no neg-head clause -> ub = 1
            float m  = mT[n * Bsz + b];
            float lo = fminf(lb, ub), hi = fmaxf(lb, ub);
            out[b * NCsz + atoms[n]] = fmaxf(lo, fminf(hi, m));
        }
    } else {
        __shared__ char isatom[NCsz];
        int p = blk - Nsz;                           // [0, 64)
        for (int i = tid; i < NCsz; i += NT2) isatom[i] = 0;
        __syncthreads();
        isatom[atoms[tid]] = 1;                      // NT2 == Nsz: one scatter per thread
        __syncthreads();
        for (int k = 0; k < 4; k++) {
            int t = p * (4 * NT2) + k * NT2 + tid;   // [0, 131072) = B*NC
            int b = t >> 10, j = t & (NCsz - 1);     // j fast -> coalesced
            if (!isatom[j]) out[b * NCsz + j] = preds[b * NCsz + j];
        }
    }
}

extern "C" void kernel_launch(void* const* d_in, const int* in_sizes, int n_in,
                              void* d_out, int out_size, void* d_ws, size_t ws_size,
                              hipStream_t stream)
{
    const float* preds    = (const float*)d_in[0];
    const float* pos_head = (const float*)d_in[1];
    const float* neg_head = (const float*)d_in[2];
    const float* pos_body = (const float*)d_in[3];
    const float* neg_body = (const float*)d_in[4];
    const int*   atoms    = (const int*)d_in[5];
    float* out = (float*)d_out;

    char* ws = (char*)d_ws;
    float* mT       = (float*)(ws);                  // 65536 f32, mT[n][b]
    int*   pos_list = (int*)(ws + 65536u * 4);       // C*CAP
    int*   neg_list = (int*)(ws + 131072u * 4);      // C*CAP
    int*   pos_cnt  = (int*)(ws + 196608u * 4);      // C
    int*   neg_cnt  = pos_cnt + Csz;                 // C
    int*   head_of  = neg_cnt + Csz;                 // C   (~790 KB total)

    k_scan<<<512, 256, 0, stream>>>(preds, pos_head, neg_head, pos_body, neg_body, atoms,
                                    mT, pos_list, neg_list, pos_cnt, neg_cnt, head_of);

    k_apply<<<576, NT2, 0, stream>>>(preds, mT, pos_list, neg_list, pos_cnt, neg_cnt,
                                     head_of, atoms, out);
}

// Round 3
// 77.122 us; speedup vs baseline: 1.8191x; 1.0919x over previous
//
#include <hip/hip_runtime.h>

#define Bsz 128
#define Csz 1024
#define Nsz 512
#define NCsz 1024
#define CAP 64     // max body literals per clause per sign; E=10.2, P(>64)~0 (verified absmax=0)

// ---------------- Kernel 1: zero bounds + gather mT + clause scan + full out copy --------
// blocks   0..127: uint4-zero lbmax||ubmax (131072 u32, contiguous)
// blocks 128..383: gather mT[col][b] = preds[b][atoms[col]] (coalesced writes, L2 gather reads)
// blocks 384..639: wave-per-clause float4 scan -> literal lists + head_of[c]=(n<<1)|sign
// blocks 640..767: float4 copy preds -> out (ALL columns; atom cols overwritten by k3 later)
__global__ __launch_bounds__(256) void k_pre(
    const float* __restrict__ preds,
    const float* __restrict__ pos_head, const float* __restrict__ neg_head,
    const float* __restrict__ pos_body, const float* __restrict__ neg_body,
    const int* __restrict__ atoms,
    float* __restrict__ mT, unsigned* __restrict__ bounds,
    int* __restrict__ pos_list, int* __restrict__ neg_list,
    int* __restrict__ pos_cnt, int* __restrict__ neg_cnt,
    int* __restrict__ head_of,
    float* __restrict__ out)
{
    int blk = blockIdx.x, tid = threadIdx.x;
    if (blk < 128) {
        ((uint4*)bounds)[blk * 256 + tid] = make_uint4(0u, 0u, 0u, 0u);
    } else if (blk < 384) {
        int b   = tid & (Bsz - 1);
        int col = 2 * (blk - 128) + (tid >> 7);
        mT[col * Bsz + b] = preds[b * NCsz + atoms[col]];
    } else if (blk < 640) {
        __shared__ int cnts[4][2];
        int wave = tid >> 6, lane = tid & 63;
        int c = (blk - 384) * 4 + wave;
        if (lane == 0) { cnts[wave][0] = 0; cnts[wave][1] = 0; }
        // per-wave LDS counters, wave-ordered stream: no barrier needed (round-0-verified)
        const float4* pb4 = (const float4*)(pos_body + c * Nsz);
        const float4* nb4 = (const float4*)(neg_body + c * Nsz);
        const float4* ph4 = (const float4*)(pos_head + c * Nsz);
        const float4* nh4 = (const float4*)(neg_head + c * Nsz);
        for (int k = 0; k < 2; k++) {
            int q = k * 64 + lane;                // float4 index, n0 = 4*q
            float4 p  = pb4[q];
            float4 nb = nb4[q];
            float4 ph = ph4[q];
            float4 nh = nh4[q];
            int n0 = q * 4;
            if (p.x  != 0.f) { int s = atomicAdd(&cnts[wave][0], 1); if (s < CAP) pos_list[c * CAP + s] = n0;     }
            if (p.y  != 0.f) { int s = atomicAdd(&cnts[wave][0], 1); if (s < CAP) pos_list[c * CAP + s] = n0 + 1; }
            if (p.z  != 0.f) { int s = atomicAdd(&cnts[wave][0], 1); if (s < CAP) pos_list[c * CAP + s] = n0 + 2; }
            if (p.w  != 0.f) { int s = atomicAdd(&cnts[wave][0], 1); if (s < CAP) pos_list[c * CAP + s] = n0 + 3; }
            if (nb.x != 0.f) { int s = atomicAdd(&cnts[wave][1], 1); if (s < CAP) neg_list[c * CAP + s] = n0;     }
            if (nb.y != 0.f) { int s = atomicAdd(&cnts[wave][1], 1); if (s < CAP) neg_list[c * CAP + s] = n0 + 1; }
            if (nb.z != 0.f) { int s = atomicAdd(&cnts[wave][1], 1); if (s < CAP) neg_list[c * CAP + s] = n0 + 2; }
            if (nb.w != 0.f) { int s = atomicAdd(&cnts[wave][1], 1); if (s < CAP) neg_list[c * CAP + s] = n0 + 3; }
            if (ph.x != 0.f) head_of[c] = ((n0    ) << 1) | 1;
            if (ph.y != 0.f) head_of[c] = ((n0 + 1) << 1) | 1;
            if (ph.z != 0.f) head_of[c] = ((n0 + 2) << 1) | 1;
            if (ph.w != 0.f) head_of[c] = ((n0 + 3) << 1) | 1;
            if (nh.x != 0.f) head_of[c] = ((n0    ) << 1);
            if (nh.y != 0.f) head_of[c] = ((n0 + 1) << 1);
            if (nh.z != 0.f) head_of[c] = ((n0 + 2) << 1);
            if (nh.w != 0.f) head_of[c] = ((n0 + 3) << 1);
        }
        if (lane == 0) {
            pos_cnt[c] = min(cnts[wave][0], CAP);
            neg_cnt[c] = min(cnts[wave][1], CAP);
        }
    } else {
        int q = (blk - 640) * 256 + tid;          // [0, 32768) float4s = B*NC floats
        ((float4*)out)[q] = ((const float4*)preds)[q];
    }
}

// ---------------- Kernel 2: body_min + scatter-max into bounds ----------------
// 2 clauses per 256-thread block. Literal lists staged to LDS in one coalesced burst
// (breaks the list->mT dependent chain), then unrolled independent mT loads (ILP~4).
// bm in [0,1] -> float bits monotone -> uint atomicMax exact.
__global__ __launch_bounds__(256) void k_body(
    const float* __restrict__ mT,
    const int* __restrict__ pos_list, const int* __restrict__ neg_list,
    const int* __restrict__ pos_cnt, const int* __restrict__ neg_cnt,
    const int* __restrict__ head_of,
    unsigned* __restrict__ bounds)
{
    __shared__ int sp[2][CAP];
    __shared__ int sn[2][CAP];
    int tid = threadIdx.x;
    int cl = tid >> 7, r = tid & 127;
    int c = blockIdx.x * 2 + cl;
    if (r < CAP) sp[cl][r]       = pos_list[c * CAP + r];
    else         sn[cl][r - CAP] = neg_list[c * CAP + (r - CAP)];
    __syncthreads();

    int b  = tid & (Bsz - 1);
    int pc = pos_cnt[c], nc = neg_cnt[c];
    float acc = 0.f;
    #pragma unroll 4
    for (int e = 0; e < pc; e++) acc = fmaxf(acc, 1.f - mT[sp[cl][e] * Bsz + b]);
    #pragma unroll 4
    for (int e = 0; e < nc; e++) acc = fmaxf(acc, mT[sn[cl][e] * Bsz + b]);

    int h = head_of[c];
    unsigned* lbmax = bounds;
    unsigned* ubmax = bounds + Bsz * Nsz;
    unsigned* dst = (h & 1) ? lbmax : ubmax;      // pos head -> lb, neg head -> ub
    atomicMax(dst + (h >> 1) * Bsz + b, __float_as_uint(1.f - acc));
}

// ---------------- Kernel 3: clamp atom columns only ----------------
// 65536 threads, b-fast: mT/lb/ub reads fully coalesced; out write scattered columns
// (sorted atoms -> ~8 atoms share a 64B line, L2 merges). deg-0 atoms: lb=0, ub=1 -> m.
__global__ __launch_bounds__(256) void k_final(
    const float* __restrict__ mT,
    const unsigned* __restrict__ bounds,
    const int* __restrict__ atoms, float* __restrict__ out)
{
    int t = blockIdx.x * 256 + threadIdx.x;       // [0, 65536)
    int b = t & (Bsz - 1), n = t >> 7;
    int i = n * Bsz + b;
    float m  = mT[i];
    float lb = __uint_as_float(bounds[i]);
    float ub = 1.f - __uint_as_float(bounds[Bsz * Nsz + i]);
    float lo = fminf(lb, ub), hi = fmaxf(lb, ub);
    out[b * NCsz + atoms[n]] = fmaxf(lo, fminf(hi, m));
}

extern "C" void kernel_launch(void* const* d_in, const int* in_sizes, int n_in,
                              void* d_out, int out_size, void* d_ws, size_t ws_size,
                              hipStream_t stream)
{
    const float* preds    = (const float*)d_in[0];
    const float* pos_head = (const float*)d_in[1];
    const float* neg_head = (const float*)d_in[2];
    const float* pos_body = (const float*)d_in[3];
    const float* neg_body = (const float*)d_in[4];
    const int*   atoms    = (const int*)d_in[5];
    float* out = (float*)d_out;

    char* ws = (char*)d_ws;
    float*    mT       = (float*)(ws);                  // 65536 f32, mT[n][b]
    unsigned* bounds   = (unsigned*)(ws + 65536u * 4);  // lbmax[65536] ++ ubmax[65536]
    int*      pos_list = (int*)(ws + 196608u * 4);      // C*CAP
    int*      neg_list = (int*)(ws + 262144u * 4);      // C*CAP
    int*      pos_cnt  = (int*)(ws + 327680u * 4);      // C
    int*      neg_cnt  = pos_cnt + Csz;                 // C
    int*      head_of  = neg_cnt + Csz;                 // C   (~1.3 MB total)

    k_pre<<<768, 256, 0, stream>>>(preds, pos_head, neg_head, pos_body, neg_body, atoms,
                                   mT, bounds, pos_list, neg_list,
                                   pos_cnt, neg_cnt, head_of, out);

    k_body<<<Csz / 2, 256, 0, stream>>>(mT, pos_list, neg_list, pos_cnt, neg_cnt,
                                        head_of, bounds);

    k_final<<<256, 256, 0, stream>>>(mT, bounds, atoms, out);
}